// Round 1
// baseline (7259.507 us; speedup 1.0000x reference)
//
#include <hip/hip_runtime.h>
#include <hip/hip_bf16.h>
#include <cstdint>

typedef __bf16 bf16x8 __attribute__((ext_vector_type(8)));
typedef __bf16 bf16x4v __attribute__((ext_vector_type(4)));
typedef float f32x4 __attribute__((ext_vector_type(4)));

// ---- MFMA + async-copy helpers -------------------------------------------
static __device__ __forceinline__ f32x4 mfma16(bf16x8 a, bf16x8 b, f32x4 c) {
  return __builtin_amdgcn_mfma_f32_16x16x32_bf16(a, b, c, 0, 0, 0);
}
static __device__ __forceinline__ void gld_lds16(const void* g, void* l) {
  __builtin_amdgcn_global_load_lds(
      (__attribute__((address_space(1))) void*)(uintptr_t)g,
      (__attribute__((address_space(3))) void*)l, 16, 0, 0);
}

// ---- GEMM: C(MxN) = A(MxK) @ Bt(NxK)^T, bf16 in, fp32 accum --------------
// EPI 0: bf16 store          (QKV)
// EPI 1: bf16 relu(acc+bias) (MLP1)
// EPI 2: fp32 x += acc+bias  (out-proj / MLP2 residual)
// EPI 3: patch embed: remap row->(b,t), fp32 x = acc + patch_b + pos_emb[t]
template <int EPI>
__global__ __launch_bounds__(256) void gemm_bt(
    const __bf16* __restrict__ A, const __bf16* __restrict__ Bt, int K, int ldc,
    __bf16* __restrict__ outb, float* __restrict__ outf,
    const float* __restrict__ bias, const float* __restrict__ pos) {
  __shared__ __align__(16) __bf16 lsA[128 * 32];
  __shared__ __align__(16) __bf16 lsB[128 * 32];
  const int tid = threadIdx.x;
  const int wave = tid >> 6, lane = tid & 63;
  const int quad = lane >> 4, l16 = lane & 15;
  const long m0 = (long)blockIdx.x * 128, n0 = (long)blockIdx.y * 128;

  // staging: 512 16B-chunks per tile; chunk = i*256 + tid; row=chunk>>2, kk=chunk&3
  const int c0 = tid, c1 = 256 + tid;
  const __bf16* gA0 = A + (m0 + (c0 >> 2)) * (long)K + (c0 & 3) * 8;
  const __bf16* gA1 = A + (m0 + (c1 >> 2)) * (long)K + (c1 & 3) * 8;
  const __bf16* gB0 = Bt + (n0 + (c0 >> 2)) * (long)K + (c0 & 3) * 8;
  const __bf16* gB1 = Bt + (n0 + (c1 >> 2)) * (long)K + (c1 & 3) * 8;
  __bf16* lA0 = lsA + wave * 512;            // wave-uniform LDS bases
  __bf16* lA1 = lsA + 2048 + wave * 512;
  __bf16* lB0 = lsB + wave * 512;
  __bf16* lB1 = lsB + 2048 + wave * 512;

  const int wr = wave >> 1, wc = wave & 1;
  const __bf16* rA = lsA + (wr * 64 + l16) * 32 + quad * 8;
  const __bf16* rB = lsB + (wc * 64 + l16) * 32 + quad * 8;

  const f32x4 zz = {0.f, 0.f, 0.f, 0.f};
  f32x4 acc[4][4];
#pragma unroll
  for (int i = 0; i < 4; ++i)
#pragma unroll
    for (int j = 0; j < 4; ++j) acc[i][j] = zz;

  for (int k0 = 0; k0 < K; k0 += 32) {
    gld_lds16(gA0, lA0);
    gld_lds16(gA1, lA1);
    gld_lds16(gB0, lB0);
    gld_lds16(gB1, lB1);
    gA0 += 32; gA1 += 32; gB0 += 32; gB1 += 32;
    __syncthreads();
    bf16x8 af[4], bfr[4];
#pragma unroll
    for (int mi = 0; mi < 4; ++mi) af[mi] = *(const bf16x8*)(rA + mi * 512);
#pragma unroll
    for (int ni = 0; ni < 4; ++ni) bfr[ni] = *(const bf16x8*)(rB + ni * 512);
#pragma unroll
    for (int mi = 0; mi < 4; ++mi)
#pragma unroll
      for (int ni = 0; ni < 4; ++ni)
        acc[mi][ni] = mfma16(af[mi], bfr[ni], acc[mi][ni]);
    __syncthreads();
  }

#pragma unroll
  for (int mi = 0; mi < 4; ++mi) {
#pragma unroll
    for (int r = 0; r < 4; ++r) {
      const long row = m0 + wr * 64 + mi * 16 + quad * 4 + r;
      if (EPI == 3) {
        const int rr = (int)row;
        const int gsel = rr >= 6272 ? 1 : 0;
        const int rm = rr - gsel * 6272;
        const int bb = rm / 196, pp = rm % 196;
        const int t = gsel ? (198 + pp) : (1 + pp);
        float* xr = outf + ((long)bb * 426 + t) * 768;
        const float* pr = pos + (long)t * 768;
#pragma unroll
        for (int ni = 0; ni < 4; ++ni) {
          const long col = n0 + wc * 64 + ni * 16 + l16;
          xr[col] = acc[mi][ni][r] + bias[col] + pr[col];
        }
      } else {
#pragma unroll
        for (int ni = 0; ni < 4; ++ni) {
          const long col = n0 + wc * 64 + ni * 16 + l16;
          const float v = acc[mi][ni][r];
          if (EPI == 0) outb[row * ldc + col] = (__bf16)v;
          else if (EPI == 1) outb[row * ldc + col] = (__bf16)fmaxf(v + bias[col], 0.f);
          else outf[row * ldc + col] += v + bias[col];
        }
      }
    }
  }
}

// ---- fp32 (K,N) -> bf16 (N,K) batched transpose-pack ---------------------
__global__ __launch_bounds__(256) void transpose_pack(
    const float* __restrict__ in, __bf16* __restrict__ out, int K, int N,
    int nh, long out_ls, long out_hs) {
  __shared__ float tile[32][33];
  const int z = blockIdx.z;
  const long in_o = (long)z * K * N;
  const long out_o = (long)(z / nh) * out_ls + (long)(z % nh) * out_hs;
  const int n0 = blockIdx.x * 32, k0 = blockIdx.y * 32;
  const int tx = threadIdx.x, ty = threadIdx.y;
#pragma unroll
  for (int i = 0; i < 4; ++i)
    tile[ty + i * 8][tx] = in[in_o + (long)(k0 + ty + i * 8) * N + n0 + tx];
  __syncthreads();
#pragma unroll
  for (int i = 0; i < 4; ++i)
    out[out_o + (long)(n0 + ty + i * 8) * K + k0 + tx] = (__bf16)tile[tx][ty + i * 8];
}

// ---- patch extraction: images -> bf16 patch matrix (12544 x 768) ---------
__global__ __launch_bounds__(256) void patches_k(const float* __restrict__ img0,
                                                 const float* __restrict__ img1,
                                                 __bf16* __restrict__ out) {
  const int row = blockIdx.x;
  const int gsel = row >= 6272 ? 1 : 0;
  const int rm = row - gsel * 6272;
  const int b = rm / 196, p = rm % 196;
  const int py = p / 14, px = p % 14;
  const float* img = gsel ? img1 : img0;
#pragma unroll
  for (int i = 0; i < 3; ++i) {
    const int k = threadIdx.x + i * 256;
    const int pidx = k / 3, c = k - pidx * 3;
    const int pr = pidx >> 4, pc = pidx & 15;
    const float v = img[(((long)b * 224 + py * 16 + pr) * 224 + px * 16 + pc) * 3 + c];
    out[(long)row * 768 + k] = (__bf16)v;
  }
}

// ---- cls/goal/lang token rows + pos_emb into fp32 x ----------------------
__global__ __launch_bounds__(256) void assemble_k(
    const float* __restrict__ cls_tok, const float* __restrict__ goal_tok,
    const float* __restrict__ tok_emb, const int* __restrict__ txt,
    const float* __restrict__ pos, float* __restrict__ x) {
  const int z = blockIdx.x;
  const int b = z / 34, j = z % 34;
  const int t = (j == 0) ? 0 : (j == 1) ? 197 : (392 + j);
  const float* src = (j == 0) ? cls_tok
                   : (j == 1) ? goal_tok
                              : tok_emb + (long)txt[b * 32 + (j - 2)] * 768;
  float* dst = x + ((long)b * 426 + t) * 768;
  const float* pr = pos + (long)t * 768;
#pragma unroll
  for (int i = 0; i < 3; ++i) {
    const int k = threadIdx.x + i * 256;
    dst[k] = src[k] + pr[k];
  }
}

// ---- LayerNorm fp32 -> bf16 (one wave per row) ---------------------------
__global__ __launch_bounds__(64) void ln_k(const float* __restrict__ x,
                                           const float* __restrict__ g,
                                           const float* __restrict__ b,
                                           __bf16* __restrict__ out) {
  const int row = blockIdx.x, lane = threadIdx.x;
  const float4* xr = (const float4*)(x + (long)row * 768);
  float4 v[3];
  float s = 0.f, q = 0.f;
#pragma unroll
  for (int i = 0; i < 3; ++i) {
    v[i] = xr[lane + i * 64];
    s += v[i].x + v[i].y + v[i].z + v[i].w;
    q += v[i].x * v[i].x + v[i].y * v[i].y + v[i].z * v[i].z + v[i].w * v[i].w;
  }
#pragma unroll
  for (int o = 32; o > 0; o >>= 1) {
    s += __shfl_xor(s, o);
    q += __shfl_xor(q, o);
  }
  const float mean = s * (1.f / 768.f);
  const float var = q * (1.f / 768.f) - mean * mean;
  const float rs = rsqrtf(var + 1e-5f);
  const float4* g4 = (const float4*)g;
  const float4* b4 = (const float4*)b;
#pragma unroll
  for (int i = 0; i < 3; ++i) {
    const float4 gg = g4[lane + i * 64], bb = b4[lane + i * 64];
    bf16x4v o4;
    o4[0] = (__bf16)((v[i].x - mean) * rs * gg.x + bb.x);
    o4[1] = (__bf16)((v[i].y - mean) * rs * gg.y + bb.y);
    o4[2] = (__bf16)((v[i].z - mean) * rs * gg.z + bb.z);
    o4[3] = (__bf16)((v[i].w - mean) * rs * gg.w + bb.w);
    *(bf16x4v*)(out + (long)row * 768 + (lane + i * 64) * 4) = o4;
  }
}

// ---- V transpose per head: qkv[:,1536+h*64+e] -> vt[bh][e][448] ----------
__global__ __launch_bounds__(256) void vtrans_k(const __bf16* __restrict__ qkv,
                                                __bf16* __restrict__ vt) {
  __shared__ __bf16 tile[64][66];
  const int bh = blockIdx.x;
  const int b = bh / 12, h = bh % 12;
  const int s0 = blockIdx.y * 64;
  const int t = threadIdx.x;
  const int sr = t >> 2, part = t & 3;
  const __bf16* src = qkv + ((long)(b * 426 + s0 + sr)) * 2304 + 1536 + h * 64 + part * 16;
#pragma unroll
  for (int j = 0; j < 16; ++j) tile[sr][part * 16 + j] = src[j];
  __syncthreads();
  __bf16* dst = vt + ((long)bh * 64 + sr) * 448 + s0 + part * 16;
#pragma unroll
  for (int j = 0; j < 16; ++j) {
    const int s = s0 + part * 16 + j;
    dst[j] = (s < 426) ? tile[part * 16 + j][sr] : (__bf16)0.f;
  }
}

// ---- flash attention: one wave per (b,h,16-query tile) -------------------
__global__ __launch_bounds__(64) void attn_k(const __bf16* __restrict__ qkv,
                                             const __bf16* __restrict__ vt,
                                             __bf16* __restrict__ attout) {
  const int lane = threadIdx.x;
  const int quad = lane >> 4, l16 = lane & 15;
  const int bh = blockIdx.x;
  const int b = bh / 12, h = bh % 12;
  const int q0 = blockIdx.y * 16;
  __shared__ __align__(16) __bf16 pbuf[16 * 32];

  const long qrow = ((long)(b * 426 + q0 + l16)) * 2304 + h * 64;
  const bf16x8 aq0 = *(const bf16x8*)(qkv + qrow + quad * 8);
  const bf16x8 aq1 = *(const bf16x8*)(qkv + qrow + 32 + quad * 8);

  const f32x4 zz = {0.f, 0.f, 0.f, 0.f};
  f32x4 o[4] = {zz, zz, zz, zz};
  float m_i[4] = {-3e38f, -3e38f, -3e38f, -3e38f};
  float l_i[4] = {0.f, 0.f, 0.f, 0.f};
  const float scale = 0.03608439182435161f;  // 768^-0.5 (ref scales by D)

  for (int kc = 0; kc < 14; ++kc) {
    const int kbase = kc * 32;
    f32x4 s0 = zz, s1 = zz;
    const long krow0 = ((long)(b * 426 + kbase + l16)) * 2304 + 768 + h * 64;
    const long krow1 = krow0 + 16 * 2304;
    s0 = mfma16(aq0, *(const bf16x8*)(qkv + krow0 + quad * 8), s0);
    s0 = mfma16(aq1, *(const bf16x8*)(qkv + krow0 + 32 + quad * 8), s0);
    s1 = mfma16(aq0, *(const bf16x8*)(qkv + krow1 + quad * 8), s1);
    s1 = mfma16(aq1, *(const bf16x8*)(qkv + krow1 + 32 + quad * 8), s1);
    const int key0 = kbase + l16, key1 = kbase + 16 + l16;
#pragma unroll
    for (int r = 0; r < 4; ++r) {
      const float a = (key0 < 426) ? s0[r] * scale : -1e30f;
      const float c = (key1 < 426) ? s1[r] * scale : -1e30f;
      float mx = fmaxf(a, c);
#pragma unroll
      for (int w = 1; w < 16; w <<= 1) mx = fmaxf(mx, __shfl_xor(mx, w, 16));
      mx = fmaxf(mx, m_i[r]);
      const float alpha = __expf(m_i[r] - mx);
      m_i[r] = mx;
      const float p0 = __expf(a - mx), p1 = __expf(c - mx);
      float rsum = p0 + p1;
#pragma unroll
      for (int w = 1; w < 16; w <<= 1) rsum += __shfl_xor(rsum, w, 16);
      l_i[r] = l_i[r] * alpha + rsum;
      o[0][r] *= alpha; o[1][r] *= alpha; o[2][r] *= alpha; o[3][r] *= alpha;
      const int prow = quad * 4 + r;
      pbuf[prow * 32 + l16] = (__bf16)p0;
      pbuf[prow * 32 + 16 + l16] = (__bf16)p1;
    }
    __syncthreads();  // C-layout P -> A-layout via LDS
    const bf16x8 pa = *(const bf16x8*)(pbuf + l16 * 32 + quad * 8);
#pragma unroll
    for (int et = 0; et < 4; ++et) {
      const bf16x8 bv =
          *(const bf16x8*)(vt + ((long)bh * 64 + et * 16 + l16) * 448 + kbase + quad * 8);
      o[et] = mfma16(pa, bv, o[et]);
    }
    __syncthreads();
  }
#pragma unroll
  for (int r = 0; r < 4; ++r) {
    const int q = q0 + quad * 4 + r;
    if (q < 426) {
      const float inv = 1.f / l_i[r];
      __bf16* dst = attout + ((long)(b * 426 + q)) * 768 + h * 64 + l16;
#pragma unroll
      for (int et = 0; et < 4; ++et) dst[et * 16] = (__bf16)(o[et][r] * inv);
    }
  }
}

// ---- action head ---------------------------------------------------------
__global__ __launch_bounds__(256) void head1_k(const __bf16* __restrict__ xn,
                                               const float* __restrict__ W1,
                                               const float* __restrict__ b1,
                                               float* __restrict__ hh) {
  const int id = blockIdx.x * 256 + threadIdx.x;
  const int r = id / 3072, n = id % 3072;
  const __bf16* c = xn + (long)r * 426 * 768;
  float s = 0.f;
  for (int k = 0; k < 768; ++k) s += (float)c[k] * W1[(long)k * 3072 + n];
  hh[(long)r * 3072 + n] = fmaxf(s + b1[n], 0.f);
}

__global__ __launch_bounds__(256) void head2_k(const float* __restrict__ hh,
                                               const float* __restrict__ W2,
                                               const float* __restrict__ b2,
                                               float* __restrict__ out) {
  const int t = threadIdx.x;
  if (t >= 224) return;
  const int r = t / 7, n = t % 7;
  float s = 0.f;
  for (int k = 0; k < 3072; ++k) s += hh[(long)r * 3072 + k] * W2[(long)k * 7 + n];
  out[r * 7 + n] = s + b2[n];
}

// ---- driver --------------------------------------------------------------
extern "C" void kernel_launch(void* const* d_in, const int* in_sizes, int n_in,
                              void* d_out, int out_size, void* d_ws, size_t ws_size,
                              hipStream_t stream) {
  (void)in_sizes; (void)n_in; (void)out_size; (void)ws_size;
  const float* images   = (const float*)d_in[0];
  const float* goal_img = (const float*)d_in[1];
  const int*   txt      = (const int*)d_in[2];
  const float* patch_W  = (const float*)d_in[3];
  const float* patch_b  = (const float*)d_in[4];
  const float* tok_emb  = (const float*)d_in[5];
  const float* pos_emb  = (const float*)d_in[6];
  const float* cls_tok  = (const float*)d_in[7];
  const float* goal_tok = (const float*)d_in[8];
  const float* Wq   = (const float*)d_in[9];
  const float* Wk   = (const float*)d_in[10];
  const float* Wv   = (const float*)d_in[11];
  const float* Wo   = (const float*)d_in[12];
  const float* bo   = (const float*)d_in[13];
  const float* ln1g = (const float*)d_in[14];
  const float* ln1b = (const float*)d_in[15];
  const float* ln2g = (const float*)d_in[16];
  const float* ln2b = (const float*)d_in[17];
  const float* W1   = (const float*)d_in[18];
  const float* b1   = (const float*)d_in[19];
  const float* W2   = (const float*)d_in[20];
  const float* b2   = (const float*)d_in[21];
  const float* lnfg = (const float*)d_in[22];
  const float* lnfb = (const float*)d_in[23];
  const float* aW1  = (const float*)d_in[24];
  const float* ab1  = (const float*)d_in[25];
  const float* aW2  = (const float*)d_in[26];
  const float* ab2  = (const float*)d_in[27];

  char* base = (char*)d_ws;
  size_t off = 0;
  auto take = [&](size_t bytes) -> char* {
    char* p = base + off;
    off += (bytes + 255) & ~(size_t)255;
    return p;
  };
  float*  x     = (float*) take((size_t)13696 * 768 * 4);
  __bf16* xn    = (__bf16*)take((size_t)13696 * 768 * 2);
  __bf16* shard = (__bf16*)take((size_t)13696 * 3072 * 2);  // patches|qkv|hbuf
  __bf16* attb  = (__bf16*)take((size_t)13696 * 768 * 2);
  __bf16* vt    = (__bf16*)take((size_t)384 * 64 * 448 * 2);
  float*  hh    = (float*) take((size_t)32 * 3072 * 4);
  __bf16* wqkv  = (__bf16*)take((size_t)12 * 2304 * 768 * 2);
  __bf16* wot   = (__bf16*)take((size_t)12 * 768 * 768 * 2);
  __bf16* w1t   = (__bf16*)take((size_t)12 * 768 * 3072 * 2);
  __bf16* w2t   = (__bf16*)take((size_t)12 * 768 * 3072 * 2);
  __bf16* pwt   = (__bf16*)take((size_t)768 * 768 * 2);
  __bf16* qkv   = shard;
  __bf16* hbuf  = shard;
  __bf16* patches = shard;

  const dim3 tpb(32, 8);
  transpose_pack<<<dim3(24, 24, 1), tpb, 0, stream>>>(patch_W, pwt, 768, 768, 1, 0L, 0L);
  transpose_pack<<<dim3(2, 24, 144), tpb, 0, stream>>>(Wq, wqkv, 768, 64, 12, 1769472L, 49152L);
  transpose_pack<<<dim3(2, 24, 144), tpb, 0, stream>>>(Wk, wqkv + 589824, 768, 64, 12, 1769472L, 49152L);
  transpose_pack<<<dim3(2, 24, 144), tpb, 0, stream>>>(Wv, wqkv + 1179648, 768, 64, 12, 1769472L, 49152L);
  transpose_pack<<<dim3(24, 24, 12), tpb, 0, stream>>>(Wo, wot, 768, 768, 1, 589824L, 0L);
  transpose_pack<<<dim3(96, 24, 12), tpb, 0, stream>>>(W1, w1t, 768, 3072, 1, 2359296L, 0L);
  transpose_pack<<<dim3(24, 96, 12), tpb, 0, stream>>>(W2, w2t, 3072, 768, 1, 2359296L, 0L);

  patches_k<<<12544, 256, 0, stream>>>(images, goal_img, patches);
  assemble_k<<<1088, 256, 0, stream>>>(cls_tok, goal_tok, tok_emb, txt, pos_emb, x);
  gemm_bt<3><<<dim3(98, 6), 256, 0, stream>>>(patches, pwt, 768, 768, nullptr, x, patch_b, pos_emb);

  for (int l = 0; l < 12; ++l) {
    ln_k<<<13696, 64, 0, stream>>>(x, ln1g + l * 768, ln1b + l * 768, xn);
    gemm_bt<0><<<dim3(107, 18), 256, 0, stream>>>(xn, wqkv + (long)l * 1769472, 768, 2304,
                                                  qkv, nullptr, nullptr, nullptr);
    vtrans_k<<<dim3(384, 7), 256, 0, stream>>>(qkv, vt);
    attn_k<<<dim3(384, 27), 64, 0, stream>>>(qkv, vt, attb);
    gemm_bt<2><<<dim3(107, 6), 256, 0, stream>>>(attb, wot + (long)l * 589824, 768, 768,
                                                 nullptr, x, bo + l * 768, nullptr);
    ln_k<<<13696, 64, 0, stream>>>(x, ln2g + l * 768, ln2b + l * 768, xn);
    gemm_bt<1><<<dim3(107, 24), 256, 0, stream>>>(xn, w1t + (long)l * 2359296, 768, 3072,
                                                  hbuf, nullptr, b1 + l * 3072, nullptr);
    gemm_bt<2><<<dim3(107, 6), 256, 0, stream>>>(hbuf, w2t + (long)l * 2359296, 3072, 768,
                                                 nullptr, x, b2 + l * 768, nullptr);
  }
  ln_k<<<13696, 64, 0, stream>>>(x, lnfg, lnfb, xn);
  head1_k<<<384, 256, 0, stream>>>(xn, aW1, ab1, hh);
  head2_k<<<1, 256, 0, stream>>>(hh, aW2, ab2, (float*)d_out);
}

// Round 2
// 6497.793 us; speedup vs baseline: 1.1172x; 1.1172x over previous
//
#include <hip/hip_runtime.h>
#include <hip/hip_bf16.h>
#include <cstdint>

typedef __bf16 bf16x8 __attribute__((ext_vector_type(8)));
typedef __bf16 bf16x4v __attribute__((ext_vector_type(4)));
typedef float f32x4 __attribute__((ext_vector_type(4)));

// ---- MFMA + async-copy helpers -------------------------------------------
static __device__ __forceinline__ f32x4 mfma16(bf16x8 a, bf16x8 b, f32x4 c) {
  return __builtin_amdgcn_mfma_f32_16x16x32_bf16(a, b, c, 0, 0, 0);
}
static __device__ __forceinline__ void gld_lds16(const void* g, void* l) {
  __builtin_amdgcn_global_load_lds(
      (__attribute__((address_space(1))) void*)(uintptr_t)g,
      (__attribute__((address_space(3))) void*)l, 16, 0, 0);
}

// ---- GEMM: C(MxN) = A(MxK) @ Bt(NxK)^T, bf16 in, fp32 accum --------------
// EPI 0: bf16 store          (QKV)
// EPI 1: bf16 relu(acc+bias) (MLP1)
// EPI 2: fp32 x += acc+bias  (out-proj / MLP2 residual)
// EPI 3: patch embed: remap row->(b,t), fp32 x = acc + patch_b + pos_emb[t]
template <int EPI>
__global__ __launch_bounds__(256) void gemm_bt(
    const __bf16* __restrict__ A, const __bf16* __restrict__ Bt, int K, int ldc,
    __bf16* __restrict__ outb, float* __restrict__ outf,
    const float* __restrict__ bias, const float* __restrict__ pos) {
  __shared__ __align__(16) __bf16 lsA[128 * 32];
  __shared__ __align__(16) __bf16 lsB[128 * 32];
  const int tid = threadIdx.x;
  const int wave = tid >> 6, lane = tid & 63;
  const int quad = lane >> 4, l16 = lane & 15;
  const long m0 = (long)blockIdx.x * 128, n0 = (long)blockIdx.y * 128;

  const int c0 = tid, c1 = 256 + tid;
  const __bf16* gA0 = A + (m0 + (c0 >> 2)) * (long)K + (c0 & 3) * 8;
  const __bf16* gA1 = A + (m0 + (c1 >> 2)) * (long)K + (c1 & 3) * 8;
  const __bf16* gB0 = Bt + (n0 + (c0 >> 2)) * (long)K + (c0 & 3) * 8;
  const __bf16* gB1 = Bt + (n0 + (c1 >> 2)) * (long)K + (c1 & 3) * 8;
  __bf16* lA0 = lsA + wave * 512;
  __bf16* lA1 = lsA + 2048 + wave * 512;
  __bf16* lB0 = lsB + wave * 512;
  __bf16* lB1 = lsB + 2048 + wave * 512;

  const int wr = wave >> 1, wc = wave & 1;
  const __bf16* rA = lsA + (wr * 64 + l16) * 32 + quad * 8;
  const __bf16* rB = lsB + (wc * 64 + l16) * 32 + quad * 8;

  const f32x4 zz = {0.f, 0.f, 0.f, 0.f};
  f32x4 acc[4][4];
#pragma unroll
  for (int i = 0; i < 4; ++i)
#pragma unroll
    for (int j = 0; j < 4; ++j) acc[i][j] = zz;

  for (int k0 = 0; k0 < K; k0 += 32) {
    gld_lds16(gA0, lA0);
    gld_lds16(gA1, lA1);
    gld_lds16(gB0, lB0);
    gld_lds16(gB1, lB1);
    gA0 += 32; gA1 += 32; gB0 += 32; gB1 += 32;
    __syncthreads();
    bf16x8 af[4], bfr[4];
#pragma unroll
    for (int mi = 0; mi < 4; ++mi) af[mi] = *(const bf16x8*)(rA + mi * 512);
#pragma unroll
    for (int ni = 0; ni < 4; ++ni) bfr[ni] = *(const bf16x8*)(rB + ni * 512);
#pragma unroll
    for (int mi = 0; mi < 4; ++mi)
#pragma unroll
      for (int ni = 0; ni < 4; ++ni)
        acc[mi][ni] = mfma16(af[mi], bfr[ni], acc[mi][ni]);
    __syncthreads();
  }

#pragma unroll
  for (int mi = 0; mi < 4; ++mi) {
#pragma unroll
    for (int r = 0; r < 4; ++r) {
      const long row = m0 + wr * 64 + mi * 16 + quad * 4 + r;
      if (EPI == 3) {
        const int rr = (int)row;
        const int gsel = rr >= 6272 ? 1 : 0;
        const int rm = rr - gsel * 6272;
        const int bb = rm / 196, pp = rm % 196;
        const int t = gsel ? (198 + pp) : (1 + pp);
        float* xr = outf + ((long)bb * 426 + t) * 768;
        const float* pr = pos + (long)t * 768;
#pragma unroll
        for (int ni = 0; ni < 4; ++ni) {
          const long col = n0 + wc * 64 + ni * 16 + l16;
          xr[col] = acc[mi][ni][r] + bias[col] + pr[col];
        }
      } else {
#pragma unroll
        for (int ni = 0; ni < 4; ++ni) {
          const long col = n0 + wc * 64 + ni * 16 + l16;
          const float v = acc[mi][ni][r];
          if (EPI == 0) outb[row * ldc + col] = (__bf16)v;
          else if (EPI == 1) outb[row * ldc + col] = (__bf16)fmaxf(v + bias[col], 0.f);
          else outf[row * ldc + col] += v + bias[col];
        }
      }
    }
  }
}

// ---- fp32 (K,N) -> bf16 (N,K) batched transpose-pack ---------------------
__global__ __launch_bounds__(256) void transpose_pack(
    const float* __restrict__ in, __bf16* __restrict__ out, int K, int N,
    int nh, long out_ls, long out_hs) {
  __shared__ float tile[32][33];
  const int z = blockIdx.z;
  const long in_o = (long)z * K * N;
  const long out_o = (long)(z / nh) * out_ls + (long)(z % nh) * out_hs;
  const int n0 = blockIdx.x * 32, k0 = blockIdx.y * 32;
  const int tx = threadIdx.x, ty = threadIdx.y;
#pragma unroll
  for (int i = 0; i < 4; ++i)
    tile[ty + i * 8][tx] = in[in_o + (long)(k0 + ty + i * 8) * N + n0 + tx];
  __syncthreads();
#pragma unroll
  for (int i = 0; i < 4; ++i)
    out[out_o + (long)(n0 + ty + i * 8) * K + k0 + tx] = (__bf16)tile[tx][ty + i * 8];
}

// ---- patch extraction: images -> bf16 patch matrix (12544 x 768) ---------
__global__ __launch_bounds__(256) void patches_k(const float* __restrict__ img0,
                                                 const float* __restrict__ img1,
                                                 __bf16* __restrict__ out) {
  const int row = blockIdx.x;
  const int gsel = row >= 6272 ? 1 : 0;
  const int rm = row - gsel * 6272;
  const int b = rm / 196, p = rm % 196;
  const int py = p / 14, px = p % 14;
  const float* img = gsel ? img1 : img0;
#pragma unroll
  for (int i = 0; i < 3; ++i) {
    const int k = threadIdx.x + i * 256;
    const int pidx = k / 3, c = k - pidx * 3;
    const int pr = pidx >> 4, pc = pidx & 15;
    const float v = img[(((long)b * 224 + py * 16 + pr) * 224 + px * 16 + pc) * 3 + c];
    out[(long)row * 768 + k] = (__bf16)v;
  }
}

// ---- cls/goal/lang token rows + pos_emb into fp32 x ----------------------
__global__ __launch_bounds__(256) void assemble_k(
    const float* __restrict__ cls_tok, const float* __restrict__ goal_tok,
    const float* __restrict__ tok_emb, const int* __restrict__ txt,
    const float* __restrict__ pos, float* __restrict__ x) {
  const int z = blockIdx.x;
  const int b = z / 34, j = z % 34;
  const int t = (j == 0) ? 0 : (j == 1) ? 197 : (392 + j);
  const float* src = (j == 0) ? cls_tok
                   : (j == 1) ? goal_tok
                              : tok_emb + (long)txt[b * 32 + (j - 2)] * 768;
  float* dst = x + ((long)b * 426 + t) * 768;
  const float* pr = pos + (long)t * 768;
#pragma unroll
  for (int i = 0; i < 3; ++i) {
    const int k = threadIdx.x + i * 256;
    dst[k] = src[k] + pr[k];
  }
}

// ---- LayerNorm fp32 -> bf16 (one wave per row) ---------------------------
__global__ __launch_bounds__(64) void ln_k(const float* __restrict__ x,
                                           const float* __restrict__ g,
                                           const float* __restrict__ b,
                                           __bf16* __restrict__ out) {
  const int row = blockIdx.x, lane = threadIdx.x;
  const float4* xr = (const float4*)(x + (long)row * 768);
  float4 v[3];
  float s = 0.f, q = 0.f;
#pragma unroll
  for (int i = 0; i < 3; ++i) {
    v[i] = xr[lane + i * 64];
    s += v[i].x + v[i].y + v[i].z + v[i].w;
    q += v[i].x * v[i].x + v[i].y * v[i].y + v[i].z * v[i].z + v[i].w * v[i].w;
  }
#pragma unroll
  for (int o = 32; o > 0; o >>= 1) {
    s += __shfl_xor(s, o);
    q += __shfl_xor(q, o);
  }
  const float mean = s * (1.f / 768.f);
  const float var = q * (1.f / 768.f) - mean * mean;
  const float rs = rsqrtf(var + 1e-5f);
  const float4* g4 = (const float4*)g;
  const float4* b4 = (const float4*)b;
#pragma unroll
  for (int i = 0; i < 3; ++i) {
    const float4 gg = g4[lane + i * 64], bb = b4[lane + i * 64];
    bf16x4v o4;
    o4[0] = (__bf16)((v[i].x - mean) * rs * gg.x + bb.x);
    o4[1] = (__bf16)((v[i].y - mean) * rs * gg.y + bb.y);
    o4[2] = (__bf16)((v[i].z - mean) * rs * gg.z + bb.z);
    o4[3] = (__bf16)((v[i].w - mean) * rs * gg.w + bb.w);
    *(bf16x4v*)(out + (long)row * 768 + (lane + i * 64) * 4) = o4;
  }
}

// ---- V transpose per head: qkv[:,1536+h*64+e] -> vt[bh][e][448] ----------
__global__ __launch_bounds__(256) void vtrans_k(const __bf16* __restrict__ qkv,
                                                __bf16* __restrict__ vt) {
  __shared__ __bf16 tile[64][66];
  const int bh = blockIdx.x;
  const int b = bh / 12, h = bh % 12;
  const int s0 = blockIdx.y * 64;
  const int t = threadIdx.x;
  const int sr = t >> 2, part = t & 3;
  const __bf16* src = qkv + ((long)(b * 426 + s0 + sr)) * 2304 + 1536 + h * 64 + part * 16;
#pragma unroll
  for (int j = 0; j < 16; ++j) tile[sr][part * 16 + j] = src[j];
  __syncthreads();
  __bf16* dst = vt + ((long)bh * 64 + sr) * 448 + s0 + part * 16;
#pragma unroll
  for (int j = 0; j < 16; ++j) {
    const int s = s0 + part * 16 + j;
    dst[j] = (s < 426) ? tile[part * 16 + j][sr] : (__bf16)0.f;
  }
}

// ---- flash attention v2: 4 waves/WG, 64-query tile per WG, 64-key chunks -
// LDS: K-tile 8KB + Vt-tile 8KB (async-staged, XOR-swizzled, shared by all
// 4 waves) + per-wave P roundtrip buffers 4x2KB. 24KB -> 6 WG/CU.
__global__ __launch_bounds__(256) void attn_k(const __bf16* __restrict__ qkv,
                                              const __bf16* __restrict__ vt,
                                              __bf16* __restrict__ attout) {
  __shared__ __align__(16) __bf16 lds[8192 + 4096];  // K(4096) | V(4096) | P(4096)
  const int tid = threadIdx.x;
  const int wave = tid >> 6, lane = tid & 63;
  const int quad = lane >> 4, l16 = lane & 15;
  const int bh = blockIdx.x;
  const int b = bh / 12, h = bh % 12;
  const int q0 = blockIdx.y * 64 + wave * 16;  // this wave's 16 queries
  const long b426 = (long)b * 426;

  // swizzle offsets for reading 16B frags from [row][64] tiles: row&7 == l16&7
  const int swz0 = ((quad) ^ (l16 & 7)) * 8;        // kk=0: part=quad
  const int swz1 = ((4 + quad) ^ (l16 & 7)) * 8;    // kk=1: part=4+quad
  __bf16* lsK = lds;
  __bf16* lsV = lds + 4096;
  __bf16* lsP = lds + 8192 + wave * 1024;

  // staging source pointers (advance per 64-key chunk)
  const __bf16* gsrc[4];
  long gstep[4];
#pragma unroll
  for (int s = 0; s < 4; ++s) {
    const int c = s * 256 + tid;
    if (c < 512) {  // K region: slot c holds (key=c>>3, part=(c&7)^(key&7))
      const int key = c >> 3, part = (c & 7) ^ (key & 7);
      gsrc[s] = qkv + (b426 + key) * 2304 + 768 + h * 64 + part * 8;
      gstep[s] = 64 * 2304;
    } else {        // V region: slot holds (e=cv>>3, part=(cv&7)^(e&7))
      const int cv = c - 512;
      const int e = cv >> 3, part = (cv & 7) ^ (e & 7);
      gsrc[s] = vt + ((long)bh * 64 + e) * 448 + part * 8;
      gstep[s] = 64;
    }
  }
  __bf16* ldst[4];
#pragma unroll
  for (int s = 0; s < 4; ++s) ldst[s] = lds + (s * 256 + (tid & ~63)) * 8;

  // Q fragments (held in registers for the whole kernel)
  const long qrow = (b426 + q0 + l16) * 2304 + h * 64;
  const bf16x8 aq0 = *(const bf16x8*)(qkv + qrow + quad * 8);
  const bf16x8 aq1 = *(const bf16x8*)(qkv + qrow + 32 + quad * 8);

  const f32x4 zz = {0.f, 0.f, 0.f, 0.f};
  f32x4 o[4] = {zz, zz, zz, zz};
  float m_i[4] = {-3e38f, -3e38f, -3e38f, -3e38f};
  float l_i[4] = {0.f, 0.f, 0.f, 0.f};
  const float scale = 0.03608439182435161f;  // 768^-0.5

  for (int kc = 0; kc < 7; ++kc) {
    const int kbase = kc * 64;
    __syncthreads();  // previous chunk's LDS reads complete
#pragma unroll
    for (int s = 0; s < 4; ++s) {
      gld_lds16(gsrc[s], ldst[s]);
      gsrc[s] += gstep[s];
    }
    __syncthreads();  // staging complete (barrier drains vmcnt)

    // QK^T: 64 keys, B-frag from swizzled lsK
    f32x4 s4[4] = {zz, zz, zz, zz};
#pragma unroll
    for (int nt = 0; nt < 4; ++nt) {
      const __bf16* kb = lsK + (nt * 16 + l16) * 64;
      s4[nt] = mfma16(aq0, *(const bf16x8*)(kb + swz0), s4[nt]);
      s4[nt] = mfma16(aq1, *(const bf16x8*)(kb + swz1), s4[nt]);
    }

    // online softmax over this 64-key chunk
    const int lim = 426 - kbase - l16;  // key nt*16+l16 valid iff nt*16 < lim
#pragma unroll
    for (int r = 0; r < 4; ++r) {
      float a0 = (0 < lim)  ? s4[0][r] * scale : -1e30f;
      float a1 = (16 < lim) ? s4[1][r] * scale : -1e30f;
      float a2 = (32 < lim) ? s4[2][r] * scale : -1e30f;
      float a3 = (48 < lim) ? s4[3][r] * scale : -1e30f;
      float mx = fmaxf(fmaxf(a0, a1), fmaxf(a2, a3));
#pragma unroll
      for (int w = 1; w < 16; w <<= 1) mx = fmaxf(mx, __shfl_xor(mx, w, 16));
      mx = fmaxf(mx, m_i[r]);
      const float alpha = __expf(m_i[r] - mx);
      m_i[r] = mx;
      const float p0 = __expf(a0 - mx), p1 = __expf(a1 - mx);
      const float p2 = __expf(a2 - mx), p3 = __expf(a3 - mx);
      float rs = (p0 + p1) + (p2 + p3);
#pragma unroll
      for (int w = 1; w < 16; w <<= 1) rs += __shfl_xor(rs, w, 16);
      l_i[r] = l_i[r] * alpha + rs;
      o[0][r] *= alpha; o[1][r] *= alpha; o[2][r] *= alpha; o[3][r] *= alpha;
      // store P row (swizzled): col = nt*16+l16, chunkcol = nt*2+(l16>>3)
      const int rowb = quad * 4 + r;
      __bf16* pb = lsP + rowb * 64 + (l16 & 7);
      const int l8 = l16 >> 3, rx = rowb & 7;
      pb[((0 + l8) ^ rx) * 8] = (__bf16)p0;
      pb[((2 + l8) ^ rx) * 8] = (__bf16)p1;
      pb[((4 + l8) ^ rx) * 8] = (__bf16)p2;
      pb[((6 + l8) ^ rx) * 8] = (__bf16)p3;
    }

    // P (A-layout) and Vt (B-frags) -> PV accumulate
    const bf16x8 pa0 = *(const bf16x8*)(lsP + l16 * 64 + swz0);
    const bf16x8 pa1 = *(const bf16x8*)(lsP + l16 * 64 + swz1);
#pragma unroll
    for (int et = 0; et < 4; ++et) {
      const __bf16* vb = lsV + (et * 16 + l16) * 64;
      o[et] = mfma16(pa0, *(const bf16x8*)(vb + swz0), o[et]);
      o[et] = mfma16(pa1, *(const bf16x8*)(vb + swz1), o[et]);
    }
  }

#pragma unroll
  for (int r = 0; r < 4; ++r) {
    const int q = q0 + quad * 4 + r;
    if (q < 426) {
      const float inv = 1.f / l_i[r];
      __bf16* dst = attout + (b426 + q) * 768 + h * 64 + l16;
#pragma unroll
      for (int et = 0; et < 4; ++et) dst[et * 16] = (__bf16)(o[et][r] * inv);
    }
  }
}

// ---- action head ---------------------------------------------------------
__global__ __launch_bounds__(256) void head1_k(const __bf16* __restrict__ xn,
                                               const float* __restrict__ W1,
                                               const float* __restrict__ b1,
                                               float* __restrict__ hh) {
  const int id = blockIdx.x * 256 + threadIdx.x;
  const int r = id / 3072, n = id % 3072;
  const __bf16* c = xn + (long)r * 426 * 768;
  float s = 0.f;
  for (int k = 0; k < 768; ++k) s += (float)c[k] * W1[(long)k * 3072 + n];
  hh[(long)r * 3072 + n] = fmaxf(s + b1[n], 0.f);
}

__global__ __launch_bounds__(256) void head2_k(const float* __restrict__ hh,
                                               const float* __restrict__ W2,
                                               const float* __restrict__ b2,
                                               float* __restrict__ out) {
  const int t = threadIdx.x;
  if (t >= 224) return;
  const int r = t / 7, n = t % 7;
  float s = 0.f;
  for (int k = 0; k < 3072; ++k) s += hh[(long)r * 3072 + k] * W2[(long)k * 7 + n];
  out[r * 7 + n] = s + b2[n];
}

// ---- driver --------------------------------------------------------------
extern "C" void kernel_launch(void* const* d_in, const int* in_sizes, int n_in,
                              void* d_out, int out_size, void* d_ws, size_t ws_size,
                              hipStream_t stream) {
  (void)in_sizes; (void)n_in; (void)out_size; (void)ws_size;
  const float* images   = (const float*)d_in[0];
  const float* goal_img = (const float*)d_in[1];
  const int*   txt      = (const int*)d_in[2];
  const float* patch_W  = (const float*)d_in[3];
  const float* patch_b  = (const float*)d_in[4];
  const float* tok_emb  = (const float*)d_in[5];
  const float* pos_emb  = (const float*)d_in[6];
  const float* cls_tok  = (const float*)d_in[7];
  const float* goal_tok = (const float*)d_in[8];
  const float* Wq   = (const float*)d_in[9];
  const float* Wk   = (const float*)d_in[10];
  const float* Wv   = (const float*)d_in[11];
  const float* Wo   = (const float*)d_in[12];
  const float* bo   = (const float*)d_in[13];
  const float* ln1g = (const float*)d_in[14];
  const float* ln1b = (const float*)d_in[15];
  const float* ln2g = (const float*)d_in[16];
  const float* ln2b = (const float*)d_in[17];
  const float* W1   = (const float*)d_in[18];
  const float* b1   = (const float*)d_in[19];
  const float* W2   = (const float*)d_in[20];
  const float* b2   = (const float*)d_in[21];
  const float* lnfg = (const float*)d_in[22];
  const float* lnfb = (const float*)d_in[23];
  const float* aW1  = (const float*)d_in[24];
  const float* ab1  = (const float*)d_in[25];
  const float* aW2  = (const float*)d_in[26];
  const float* ab2  = (const float*)d_in[27];

  char* base = (char*)d_ws;
  size_t off = 0;
  auto take = [&](size_t bytes) -> char* {
    char* p = base + off;
    off += (bytes + 255) & ~(size_t)255;
    return p;
  };
  float*  x     = (float*) take((size_t)13696 * 768 * 4);
  __bf16* xn    = (__bf16*)take((size_t)13696 * 768 * 2);
  __bf16* shard = (__bf16*)take((size_t)13696 * 3072 * 2);  // patches|qkv|hbuf
  __bf16* attb  = (__bf16*)take((size_t)13696 * 768 * 2);
  __bf16* vt    = (__bf16*)take((size_t)384 * 64 * 448 * 2);
  float*  hh    = (float*) take((size_t)32 * 3072 * 4);
  __bf16* wqkv  = (__bf16*)take((size_t)12 * 2304 * 768 * 2);
  __bf16* wot   = (__bf16*)take((size_t)12 * 768 * 768 * 2);
  __bf16* w1t   = (__bf16*)take((size_t)12 * 768 * 3072 * 2);
  __bf16* w2t   = (__bf16*)take((size_t)12 * 768 * 3072 * 2);
  __bf16* pwt   = (__bf16*)take((size_t)768 * 768 * 2);
  __bf16* qkv   = shard;
  __bf16* hbuf  = shard;
  __bf16* patches = shard;

  const dim3 tpb(32, 8);
  transpose_pack<<<dim3(24, 24, 1), tpb, 0, stream>>>(patch_W, pwt, 768, 768, 1, 0L, 0L);
  transpose_pack<<<dim3(2, 24, 144), tpb, 0, stream>>>(Wq, wqkv, 768, 64, 12, 1769472L, 49152L);
  transpose_pack<<<dim3(2, 24, 144), tpb, 0, stream>>>(Wk, wqkv + 589824, 768, 64, 12, 1769472L, 49152L);
  transpose_pack<<<dim3(2, 24, 144), tpb, 0, stream>>>(Wv, wqkv + 1179648, 768, 64, 12, 1769472L, 49152L);
  transpose_pack<<<dim3(24, 24, 12), tpb, 0, stream>>>(Wo, wot, 768, 768, 1, 589824L, 0L);
  transpose_pack<<<dim3(96, 24, 12), tpb, 0, stream>>>(W1, w1t, 768, 3072, 1, 2359296L, 0L);
  transpose_pack<<<dim3(24, 96, 12), tpb, 0, stream>>>(W2, w2t, 3072, 768, 1, 2359296L, 0L);

  patches_k<<<12544, 256, 0, stream>>>(images, goal_img, patches);
  assemble_k<<<1088, 256, 0, stream>>>(cls_tok, goal_tok, tok_emb, txt, pos_emb, x);
  gemm_bt<3><<<dim3(98, 6), 256, 0, stream>>>(patches, pwt, 768, 768, nullptr, x, patch_b, pos_emb);

  for (int l = 0; l < 12; ++l) {
    ln_k<<<13696, 64, 0, stream>>>(x, ln1g + l * 768, ln1b + l * 768, xn);
    gemm_bt<0><<<dim3(107, 18), 256, 0, stream>>>(xn, wqkv + (long)l * 1769472, 768, 2304,
                                                  qkv, nullptr, nullptr, nullptr);
    vtrans_k<<<dim3(384, 7), 256, 0, stream>>>(qkv, vt);
    attn_k<<<dim3(384, 7), 256, 0, stream>>>(qkv, vt, attb);
    gemm_bt<2><<<dim3(107, 6), 256, 0, stream>>>(attb, wot + (long)l * 589824, 768, 768,
                                                 nullptr, x, bo + l * 768, nullptr);
    ln_k<<<13696, 64, 0, stream>>>(x, ln2g + l * 768, ln2b + l * 768, xn);
    gemm_bt<1><<<dim3(107, 24), 256, 0, stream>>>(xn, w1t + (long)l * 2359296, 768, 3072,
                                                  hbuf, nullptr, b1 + l * 3072, nullptr);
    gemm_bt<2><<<dim3(107, 6), 256, 0, stream>>>(hbuf, w2t + (long)l * 2359296, 3072, 768,
                                                 nullptr, x, b2 + l * 768, nullptr);
  }
  ln_k<<<13696, 64, 0, stream>>>(x, lnfg, lnfb, xn);
  head1_k<<<384, 256, 0, stream>>>(xn, aW1, ab1, hh);
  head2_k<<<1, 256, 0, stream>>>(hh, aW2, ab2, (float*)d_out);
}

// Round 3
// 5826.934 us; speedup vs baseline: 1.2459x; 1.1151x over previous
//
#include <hip/hip_runtime.h>
#include <hip/hip_bf16.h>
#include <cstdint>

typedef __bf16 bf16x8 __attribute__((ext_vector_type(8)));
typedef __bf16 bf16x4v __attribute__((ext_vector_type(4)));
typedef float f32x4 __attribute__((ext_vector_type(4)));

// ---- MFMA + async-copy helpers -------------------------------------------
static __device__ __forceinline__ f32x4 mfma16(bf16x8 a, bf16x8 b, f32x4 c) {
  return __builtin_amdgcn_mfma_f32_16x16x32_bf16(a, b, c, 0, 0, 0);
}
static __device__ __forceinline__ void gld_lds16(const void* g, void* l) {
  __builtin_amdgcn_global_load_lds(
      (__attribute__((address_space(1))) void*)(uintptr_t)g,
      (__attribute__((address_space(3))) void*)l, 16, 0, 0);
}

// ---- GEMM: C(MxN) = A(MxK) @ Bt(NxK)^T, bf16 in, fp32 accum --------------
// 1-D grid = 8 * rpx * nY blocks; XCD-aware swizzle:
//   MODE 0 (col-fastest): row-tile's nY col-blocks adjacent -> same XCD,
//           concurrent -> A-tile fetched once (big-A, small-grid shapes).
//   MODE 1 (row-fastest): XCD's A-slice (rpx tiles) L2-resident across the
//           whole col sweep (K=768 shapes, slice ~2.7MB).
// EPI 0: bf16 store; 1: bf16 relu(acc+bias); 2: fp32 x += acc+bias;
// EPI 3: patch embed remap + patch_b + pos_emb.
template <int EPI, int MODE>
__global__ __launch_bounds__(256) void gemm_bt(
    const __bf16* __restrict__ A, const __bf16* __restrict__ Bt, int K, int ldc,
    int M, int nY,
    __bf16* __restrict__ outb, float* __restrict__ outf,
    const float* __restrict__ bias, const float* __restrict__ pos) {
  __shared__ __align__(16) __bf16 lsA[128 * 32];
  __shared__ __align__(16) __bf16 lsB[128 * 32];
  const int id = blockIdx.x;
  const int xcd = id & 7;
  const int j = id >> 3;
  const int rpx = (int)gridDim.x / (8 * nY);
  int bx, by;
  if (MODE == 0) { bx = xcd * rpx + j / nY; by = j % nY; }
  else           { by = j / rpx;            bx = xcd * rpx + j % rpx; }
  const long m0 = (long)bx * 128, n0 = (long)by * 128;
  if (m0 >= M) return;

  const int tid = threadIdx.x;
  const int wave = tid >> 6, lane = tid & 63;
  const int quad = lane >> 4, l16 = lane & 15;

  const int c0 = tid, c1 = 256 + tid;
  const __bf16* gA0 = A + (m0 + (c0 >> 2)) * (long)K + (c0 & 3) * 8;
  const __bf16* gA1 = A + (m0 + (c1 >> 2)) * (long)K + (c1 & 3) * 8;
  const __bf16* gB0 = Bt + (n0 + (c0 >> 2)) * (long)K + (c0 & 3) * 8;
  const __bf16* gB1 = Bt + (n0 + (c1 >> 2)) * (long)K + (c1 & 3) * 8;
  __bf16* lA0 = lsA + wave * 512;
  __bf16* lA1 = lsA + 2048 + wave * 512;
  __bf16* lB0 = lsB + wave * 512;
  __bf16* lB1 = lsB + 2048 + wave * 512;

  const int wr = wave >> 1, wc = wave & 1;
  const __bf16* rA = lsA + (wr * 64 + l16) * 32 + quad * 8;
  const __bf16* rB = lsB + (wc * 64 + l16) * 32 + quad * 8;

  const f32x4 zz = {0.f, 0.f, 0.f, 0.f};
  f32x4 acc[4][4];
#pragma unroll
  for (int i = 0; i < 4; ++i)
#pragma unroll
    for (int jj = 0; jj < 4; ++jj) acc[i][jj] = zz;

  for (int k0 = 0; k0 < K; k0 += 32) {
    gld_lds16(gA0, lA0);
    gld_lds16(gA1, lA1);
    gld_lds16(gB0, lB0);
    gld_lds16(gB1, lB1);
    gA0 += 32; gA1 += 32; gB0 += 32; gB1 += 32;
    __syncthreads();
    bf16x8 af[4], bfr[4];
#pragma unroll
    for (int mi = 0; mi < 4; ++mi) af[mi] = *(const bf16x8*)(rA + mi * 512);
#pragma unroll
    for (int ni = 0; ni < 4; ++ni) bfr[ni] = *(const bf16x8*)(rB + ni * 512);
#pragma unroll
    for (int mi = 0; mi < 4; ++mi)
#pragma unroll
      for (int ni = 0; ni < 4; ++ni)
        acc[mi][ni] = mfma16(af[mi], bfr[ni], acc[mi][ni]);
    __syncthreads();
  }

#pragma unroll
  for (int mi = 0; mi < 4; ++mi) {
#pragma unroll
    for (int r = 0; r < 4; ++r) {
      const long row = m0 + wr * 64 + mi * 16 + quad * 4 + r;
      if (EPI == 3) {
        const int rr = (int)row;
        const int gsel = rr >= 6272 ? 1 : 0;
        const int rm = rr - gsel * 6272;
        const int bb = rm / 196, pp = rm % 196;
        const int t = gsel ? (198 + pp) : (1 + pp);
        float* xr = outf + ((long)bb * 426 + t) * 768;
        const float* pr = pos + (long)t * 768;
#pragma unroll
        for (int ni = 0; ni < 4; ++ni) {
          const long col = n0 + wc * 64 + ni * 16 + l16;
          xr[col] = acc[mi][ni][r] + bias[col] + pr[col];
        }
      } else {
#pragma unroll
        for (int ni = 0; ni < 4; ++ni) {
          const long col = n0 + wc * 64 + ni * 16 + l16;
          const float v = acc[mi][ni][r];
          if (EPI == 0) outb[row * ldc + col] = (__bf16)v;
          else if (EPI == 1) outb[row * ldc + col] = (__bf16)fmaxf(v + bias[col], 0.f);
          else outf[row * ldc + col] += v + bias[col];
        }
      }
    }
  }
}

// ---- fp32 (K,N) -> bf16 (N,K) batched transpose-pack ---------------------
__global__ __launch_bounds__(256) void transpose_pack(
    const float* __restrict__ in, __bf16* __restrict__ out, int K, int N,
    int nh, long out_ls, long out_hs) {
  __shared__ float tile[32][33];
  const int z = blockIdx.z;
  const long in_o = (long)z * K * N;
  const long out_o = (long)(z / nh) * out_ls + (long)(z % nh) * out_hs;
  const int n0 = blockIdx.x * 32, k0 = blockIdx.y * 32;
  const int tx = threadIdx.x, ty = threadIdx.y;
#pragma unroll
  for (int i = 0; i < 4; ++i)
    tile[ty + i * 8][tx] = in[in_o + (long)(k0 + ty + i * 8) * N + n0 + tx];
  __syncthreads();
#pragma unroll
  for (int i = 0; i < 4; ++i)
    out[out_o + (long)(n0 + ty + i * 8) * K + k0 + tx] = (__bf16)tile[tx][ty + i * 8];
}

// ---- patch extraction: images -> bf16 patch matrix (12544 x 768) ---------
__global__ __launch_bounds__(256) void patches_k(const float* __restrict__ img0,
                                                 const float* __restrict__ img1,
                                                 __bf16* __restrict__ out) {
  const int row = blockIdx.x;
  const int gsel = row >= 6272 ? 1 : 0;
  const int rm = row - gsel * 6272;
  const int b = rm / 196, p = rm % 196;
  const int py = p / 14, px = p % 14;
  const float* img = gsel ? img1 : img0;
#pragma unroll
  for (int i = 0; i < 3; ++i) {
    const int k = threadIdx.x + i * 256;
    const int pidx = k / 3, c = k - pidx * 3;
    const int pr = pidx >> 4, pc = pidx & 15;
    const float v = img[(((long)b * 224 + py * 16 + pr) * 224 + px * 16 + pc) * 3 + c];
    out[(long)row * 768 + k] = (__bf16)v;
  }
}

// ---- cls/goal/lang token rows + pos_emb into fp32 x ----------------------
__global__ __launch_bounds__(256) void assemble_k(
    const float* __restrict__ cls_tok, const float* __restrict__ goal_tok,
    const float* __restrict__ tok_emb, const int* __restrict__ txt,
    const float* __restrict__ pos, float* __restrict__ x) {
  const int z = blockIdx.x;
  const int b = z / 34, j = z % 34;
  const int t = (j == 0) ? 0 : (j == 1) ? 197 : (392 + j);
  const float* src = (j == 0) ? cls_tok
                   : (j == 1) ? goal_tok
                              : tok_emb + (long)txt[b * 32 + (j - 2)] * 768;
  float* dst = x + ((long)b * 426 + t) * 768;
  const float* pr = pos + (long)t * 768;
#pragma unroll
  for (int i = 0; i < 3; ++i) {
    const int k = threadIdx.x + i * 256;
    dst[k] = src[k] + pr[k];
  }
}

// ---- LayerNorm fp32 -> bf16 (one wave per row) ---------------------------
__global__ __launch_bounds__(64) void ln_k(const float* __restrict__ x,
                                           const float* __restrict__ g,
                                           const float* __restrict__ b,
                                           __bf16* __restrict__ out) {
  const int row = blockIdx.x, lane = threadIdx.x;
  const float4* xr = (const float4*)(x + (long)row * 768);
  float4 v[3];
  float s = 0.f, q = 0.f;
#pragma unroll
  for (int i = 0; i < 3; ++i) {
    v[i] = xr[lane + i * 64];
    s += v[i].x + v[i].y + v[i].z + v[i].w;
    q += v[i].x * v[i].x + v[i].y * v[i].y + v[i].z * v[i].z + v[i].w * v[i].w;
  }
#pragma unroll
  for (int o = 32; o > 0; o >>= 1) {
    s += __shfl_xor(s, o);
    q += __shfl_xor(q, o);
  }
  const float mean = s * (1.f / 768.f);
  const float var = q * (1.f / 768.f) - mean * mean;
  const float rs = rsqrtf(var + 1e-5f);
  const float4* g4 = (const float4*)g;
  const float4* b4 = (const float4*)b;
#pragma unroll
  for (int i = 0; i < 3; ++i) {
    const float4 gg = g4[lane + i * 64], bb = b4[lane + i * 64];
    bf16x4v o4;
    o4[0] = (__bf16)((v[i].x - mean) * rs * gg.x + bb.x);
    o4[1] = (__bf16)((v[i].y - mean) * rs * gg.y + bb.y);
    o4[2] = (__bf16)((v[i].z - mean) * rs * gg.z + bb.z);
    o4[3] = (__bf16)((v[i].w - mean) * rs * gg.w + bb.w);
    *(bf16x4v*)(out + (long)row * 768 + (lane + i * 64) * 4) = o4;
  }
}

// ---- V transpose per head: qkv[:,1536+h*64+e] -> vt[bh][e][448] ----------
__global__ __launch_bounds__(256) void vtrans_k(const __bf16* __restrict__ qkv,
                                                __bf16* __restrict__ vt) {
  __shared__ __bf16 tile[64][66];
  const int bh = blockIdx.x;
  const int b = bh / 12, h = bh % 12;
  const int s0 = blockIdx.y * 64;
  const int t = threadIdx.x;
  const int sr = t >> 2, part = t & 3;
  const __bf16* src = qkv + ((long)(b * 426 + s0 + sr)) * 2304 + 1536 + h * 64 + part * 16;
#pragma unroll
  for (int j = 0; j < 16; ++j) tile[sr][part * 16 + j] = src[j];
  __syncthreads();
  __bf16* dst = vt + ((long)bh * 64 + sr) * 448 + s0 + part * 16;
#pragma unroll
  for (int j = 0; j < 16; ++j) {
    const int s = s0 + part * 16 + j;
    dst[j] = (s < 426) ? tile[part * 16 + j][sr] : (__bf16)0.f;
  }
}

// ---- flash attention: 4 waves/WG, 64-query tile, 64-key chunks -----------
__global__ __launch_bounds__(256) void attn_k(const __bf16* __restrict__ qkv,
                                              const __bf16* __restrict__ vt,
                                              __bf16* __restrict__ attout) {
  __shared__ __align__(16) __bf16 lds[8192 + 4096];  // K(4096) | V(4096) | P(4096)
  const int tid = threadIdx.x;
  const int wave = tid >> 6, lane = tid & 63;
  const int quad = lane >> 4, l16 = lane & 15;
  const int bh = blockIdx.x;
  const int b = bh / 12, h = bh % 12;
  const int q0 = blockIdx.y * 64 + wave * 16;
  const long b426 = (long)b * 426;

  const int swz0 = ((quad) ^ (l16 & 7)) * 8;
  const int swz1 = ((4 + quad) ^ (l16 & 7)) * 8;
  __bf16* lsK = lds;
  __bf16* lsV = lds + 4096;
  __bf16* lsP = lds + 8192 + wave * 1024;

  const __bf16* gsrc[4];
  long gstep[4];
#pragma unroll
  for (int s = 0; s < 4; ++s) {
    const int c = s * 256 + tid;
    if (c < 512) {
      const int key = c >> 3, part = (c & 7) ^ (key & 7);
      gsrc[s] = qkv + (b426 + key) * 2304 + 768 + h * 64 + part * 8;
      gstep[s] = 64 * 2304;
    } else {
      const int cv = c - 512;
      const int e = cv >> 3, part = (cv & 7) ^ (e & 7);
      gsrc[s] = vt + ((long)bh * 64 + e) * 448 + part * 8;
      gstep[s] = 64;
    }
  }
  __bf16* ldst[4];
#pragma unroll
  for (int s = 0; s < 4; ++s) ldst[s] = lds + (s * 256 + (tid & ~63)) * 8;

  const long qrow = (b426 + q0 + l16) * 2304 + h * 64;
  const bf16x8 aq0 = *(const bf16x8*)(qkv + qrow + quad * 8);
  const bf16x8 aq1 = *(const bf16x8*)(qkv + qrow + 32 + quad * 8);

  const f32x4 zz = {0.f, 0.f, 0.f, 0.f};
  f32x4 o[4] = {zz, zz, zz, zz};
  float m_i[4] = {-3e38f, -3e38f, -3e38f, -3e38f};
  float l_i[4] = {0.f, 0.f, 0.f, 0.f};
  const float scale = 0.03608439182435161f;  // 768^-0.5

  for (int kc = 0; kc < 7; ++kc) {
    const int kbase = kc * 64;
    __syncthreads();
#pragma unroll
    for (int s = 0; s < 4; ++s) {
      gld_lds16(gsrc[s], ldst[s]);
      gsrc[s] += gstep[s];
    }
    __syncthreads();

    f32x4 s4[4] = {zz, zz, zz, zz};
#pragma unroll
    for (int nt = 0; nt < 4; ++nt) {
      const __bf16* kb = lsK + (nt * 16 + l16) * 64;
      s4[nt] = mfma16(aq0, *(const bf16x8*)(kb + swz0), s4[nt]);
      s4[nt] = mfma16(aq1, *(const bf16x8*)(kb + swz1), s4[nt]);
    }

    const int lim = 426 - kbase - l16;
#pragma unroll
    for (int r = 0; r < 4; ++r) {
      float a0 = (0 < lim)  ? s4[0][r] * scale : -1e30f;
      float a1 = (16 < lim) ? s4[1][r] * scale : -1e30f;
      float a2 = (32 < lim) ? s4[2][r] * scale : -1e30f;
      float a3 = (48 < lim) ? s4[3][r] * scale : -1e30f;
      float mx = fmaxf(fmaxf(a0, a1), fmaxf(a2, a3));
#pragma unroll
      for (int w = 1; w < 16; w <<= 1) mx = fmaxf(mx, __shfl_xor(mx, w, 16));
      mx = fmaxf(mx, m_i[r]);
      const float alpha = __expf(m_i[r] - mx);
      m_i[r] = mx;
      const float p0 = __expf(a0 - mx), p1 = __expf(a1 - mx);
      const float p2 = __expf(a2 - mx), p3 = __expf(a3 - mx);
      float rs = (p0 + p1) + (p2 + p3);
#pragma unroll
      for (int w = 1; w < 16; w <<= 1) rs += __shfl_xor(rs, w, 16);
      l_i[r] = l_i[r] * alpha + rs;
      o[0][r] *= alpha; o[1][r] *= alpha; o[2][r] *= alpha; o[3][r] *= alpha;
      const int rowb = quad * 4 + r;
      __bf16* pb = lsP + rowb * 64 + (l16 & 7);
      const int l8 = l16 >> 3, rx = rowb & 7;
      pb[((0 + l8) ^ rx) * 8] = (__bf16)p0;
      pb[((2 + l8) ^ rx) * 8] = (__bf16)p1;
      pb[((4 + l8) ^ rx) * 8] = (__bf16)p2;
      pb[((6 + l8) ^ rx) * 8] = (__bf16)p3;
    }

    const bf16x8 pa0 = *(const bf16x8*)(lsP + l16 * 64 + swz0);
    const bf16x8 pa1 = *(const bf16x8*)(lsP + l16 * 64 + swz1);
#pragma unroll
    for (int et = 0; et < 4; ++et) {
      const __bf16* vb = lsV + (et * 16 + l16) * 64;
      o[et] = mfma16(pa0, *(const bf16x8*)(vb + swz0), o[et]);
      o[et] = mfma16(pa1, *(const bf16x8*)(vb + swz1), o[et]);
    }
  }

#pragma unroll
  for (int r = 0; r < 4; ++r) {
    const int q = q0 + quad * 4 + r;
    if (q < 426) {
      const float inv = 1.f / l_i[r];
      __bf16* dst = attout + (b426 + q) * 768 + h * 64 + l16;
#pragma unroll
      for (int et = 0; et < 4; ++et) dst[et * 16] = (__bf16)(o[et][r] * inv);
    }
  }
}

// ---- action head ---------------------------------------------------------
__global__ __launch_bounds__(256) void head1_k(const __bf16* __restrict__ xn,
                                               const float* __restrict__ W1,
                                               const float* __restrict__ b1,
                                               float* __restrict__ hh) {
  const int id = blockIdx.x * 256 + threadIdx.x;
  const int r = id / 3072, n = id % 3072;
  const __bf16* c = xn + (long)r * 426 * 768;
  float s = 0.f;
  for (int k = 0; k < 768; ++k) s += (float)c[k] * W1[(long)k * 3072 + n];
  hh[(long)r * 3072 + n] = fmaxf(s + b1[n], 0.f);
}

__global__ __launch_bounds__(256) void head2_k(const float* __restrict__ hh,
                                               const float* __restrict__ W2,
                                               const float* __restrict__ b2,
                                               float* __restrict__ out) {
  const int t = threadIdx.x;
  if (t >= 224) return;
  const int r = t / 7, n = t % 7;
  float s = 0.f;
  for (int k = 0; k < 3072; ++k) s += hh[(long)r * 3072 + k] * W2[(long)k * 7 + n];
  out[r * 7 + n] = s + b2[n];
}

// ---- driver --------------------------------------------------------------
extern "C" void kernel_launch(void* const* d_in, const int* in_sizes, int n_in,
                              void* d_out, int out_size, void* d_ws, size_t ws_size,
                              hipStream_t stream) {
  (void)in_sizes; (void)n_in; (void)out_size; (void)ws_size;
  const float* images   = (const float*)d_in[0];
  const float* goal_img = (const float*)d_in[1];
  const int*   txt      = (const int*)d_in[2];
  const float* patch_W  = (const float*)d_in[3];
  const float* patch_b  = (const float*)d_in[4];
  const float* tok_emb  = (const float*)d_in[5];
  const float* pos_emb  = (const float*)d_in[6];
  const float* cls_tok  = (const float*)d_in[7];
  const float* goal_tok = (const float*)d_in[8];
  const float* Wq   = (const float*)d_in[9];
  const float* Wk   = (const float*)d_in[10];
  const float* Wv   = (const float*)d_in[11];
  const float* Wo   = (const float*)d_in[12];
  const float* bo   = (const float*)d_in[13];
  const float* ln1g = (const float*)d_in[14];
  const float* ln1b = (const float*)d_in[15];
  const float* ln2g = (const float*)d_in[16];
  const float* ln2b = (const float*)d_in[17];
  const float* W1   = (const float*)d_in[18];
  const float* b1   = (const float*)d_in[19];
  const float* W2   = (const float*)d_in[20];
  const float* b2   = (const float*)d_in[21];
  const float* lnfg = (const float*)d_in[22];
  const float* lnfb = (const float*)d_in[23];
  const float* aW1  = (const float*)d_in[24];
  const float* ab1  = (const float*)d_in[25];
  const float* aW2  = (const float*)d_in[26];
  const float* ab2  = (const float*)d_in[27];

  char* base = (char*)d_ws;
  size_t off = 0;
  auto take = [&](size_t bytes) -> char* {
    char* p = base + off;
    off += (bytes + 255) & ~(size_t)255;
    return p;
  };
  float*  x     = (float*) take((size_t)13696 * 768 * 4);
  __bf16* xn    = (__bf16*)take((size_t)13696 * 768 * 2);
  __bf16* shard = (__bf16*)take((size_t)13696 * 3072 * 2);  // patches|qkv|hbuf
  __bf16* attb  = (__bf16*)take((size_t)13696 * 768 * 2);
  __bf16* vt    = (__bf16*)take((size_t)384 * 64 * 448 * 2);
  float*  hh    = (float*) take((size_t)32 * 3072 * 4);
  __bf16* wqkv  = (__bf16*)take((size_t)12 * 2304 * 768 * 2);
  __bf16* wot   = (__bf16*)take((size_t)12 * 768 * 768 * 2);
  __bf16* w1t   = (__bf16*)take((size_t)12 * 768 * 3072 * 2);
  __bf16* w2t   = (__bf16*)take((size_t)12 * 768 * 3072 * 2);
  __bf16* pwt   = (__bf16*)take((size_t)768 * 768 * 2);
  __bf16* qkv   = shard;
  __bf16* hbuf  = shard;
  __bf16* patches = shard;

  const dim3 tpb(32, 8);
  transpose_pack<<<dim3(24, 24, 1), tpb, 0, stream>>>(patch_W, pwt, 768, 768, 1, 0L, 0L);
  transpose_pack<<<dim3(2, 24, 144), tpb, 0, stream>>>(Wq, wqkv, 768, 64, 12, 1769472L, 49152L);
  transpose_pack<<<dim3(2, 24, 144), tpb, 0, stream>>>(Wk, wqkv + 589824, 768, 64, 12, 1769472L, 49152L);
  transpose_pack<<<dim3(2, 24, 144), tpb, 0, stream>>>(Wv, wqkv + 1179648, 768, 64, 12, 1769472L, 49152L);
  transpose_pack<<<dim3(24, 24, 12), tpb, 0, stream>>>(Wo, wot, 768, 768, 1, 589824L, 0L);
  transpose_pack<<<dim3(96, 24, 12), tpb, 0, stream>>>(W1, w1t, 768, 3072, 1, 2359296L, 0L);
  transpose_pack<<<dim3(24, 96, 12), tpb, 0, stream>>>(W2, w2t, 3072, 768, 1, 2359296L, 0L);

  patches_k<<<12544, 256, 0, stream>>>(images, goal_img, patches);
  assemble_k<<<1088, 256, 0, stream>>>(cls_tok, goal_tok, tok_emb, txt, pos_emb, x);
  // grids: 8 XCD-slots * rpx rows * nY cols (rows padded to mult of 8)
  gemm_bt<3, 1><<<8 * 13 * 6, 256, 0, stream>>>(patches, pwt, 768, 768, 12544, 6,
                                                nullptr, x, patch_b, pos_emb);

  for (int l = 0; l < 12; ++l) {
    ln_k<<<13696, 64, 0, stream>>>(x, ln1g + l * 768, ln1b + l * 768, xn);
    gemm_bt<0, 1><<<8 * 14 * 18, 256, 0, stream>>>(xn, wqkv + (long)l * 1769472, 768, 2304,
                                                   13696, 18, qkv, nullptr, nullptr, nullptr);
    vtrans_k<<<dim3(384, 7), 256, 0, stream>>>(qkv, vt);
    attn_k<<<dim3(384, 7), 256, 0, stream>>>(qkv, vt, attb);
    gemm_bt<2, 1><<<8 * 14 * 6, 256, 0, stream>>>(attb, wot + (long)l * 589824, 768, 768,
                                                  13696, 6, nullptr, x, bo + l * 768, nullptr);
    ln_k<<<13696, 64, 0, stream>>>(x, ln2g + l * 768, ln2b + l * 768, xn);
    gemm_bt<1, 1><<<8 * 14 * 24, 256, 0, stream>>>(xn, w1t + (long)l * 2359296, 768, 3072,
                                                   13696, 24, hbuf, nullptr, b1 + l * 3072, nullptr);
    gemm_bt<2, 0><<<8 * 14 * 6, 256, 0, stream>>>(hbuf, w2t + (long)l * 2359296, 3072, 768,
                                                  13696, 6, nullptr, x, b2 + l * 768, nullptr);
  }
  ln_k<<<13696, 64, 0, stream>>>(x, lnfg, lnfb, xn);
  head1_k<<<384, 256, 0, stream>>>(xn, aW1, ab1, hh);
  head2_k<<<1, 256, 0, stream>>>(hh, aW2, ab2, (float*)d_out);
}